// Round 10
// baseline (123.033 us; speedup 1.0000x reference)
//
#include <hip/hip_runtime.h>
#include <hip/hip_bf16.h>

#define BM 64
#define NROW 32768
#define NB2 (NROW / BM)  // 512 blocks
#define VV 1024
#define KD 256
#define TT 2048

#define LP_OFF 2L
#define ZQ_OFF (2L + 33554432L)
#define EM_OFF (33554434L + 8388608L)

// ws layout (floats)
#define WS_HIST 0
#define WS_CSUM 1024
#define WS_SSUM 2048
#define WS_MSUM 3072
#define WS_E8 4096              // bf16 e, 512 KB: [s8][w16][h2][q2][g'2][c32]
#define WS_Z8G (4096 + 131072)  // bf16 z, 16 MB: [blk512][oct32][row64]
#define WS_NEED_Z ((size_t)WS_Z8G * 4 + (size_t)NROW * KD * 2)

typedef __attribute__((ext_vector_type(8))) short bf16x8;
typedef __attribute__((ext_vector_type(4))) float f32x4;

__device__ __forceinline__ void gl_lds16(const void* g, void* l) {
  __builtin_amdgcn_global_load_lds(
      (const __attribute__((address_space(1))) void*)g,
      (__attribute__((address_space(3))) void*)l, 16, 0, 0);
}

__device__ __forceinline__ unsigned short f2bf(float x) {  // RNE
  unsigned u = __float_as_uint(x);
  unsigned r = ((u >> 16) & 1u) + 0x7FFFu;
  return (unsigned short)((u + r) >> 16);
}

__device__ __forceinline__ unsigned foldf(float v) {  // order-preserving
  unsigned b = __float_as_uint(v);
  return b ^ ((unsigned)((int)b >> 31) | 0x80000000u);
}
__device__ __forceinline__ float unfoldf(unsigned k) {
  unsigned s = (unsigned)((int)k >> 31);
  return __uint_as_float(k ^ (0x80000000u | (~s & 0x7FFFFFFFu)));
}

__device__ __forceinline__ int4 pack8(const float* p) {
  float4 a = *(const float4*)p;
  float4 b = *(const float4*)(p + 4);
  int4 pk;
  pk.x = f2bf(a.x) | ((unsigned)f2bf(a.y) << 16);
  pk.y = f2bf(a.z) | ((unsigned)f2bf(a.w) << 16);
  pk.z = f2bf(b.x) | ((unsigned)f2bf(b.y) << 16);
  pk.w = f2bf(b.z) | ((unsigned)f2bf(b.w) << 16);
  return pk;
}

// z8g unit t (t<1048576): blk=t>>11, oct=(t>>6)&31, row=t&63
// e8 unit t2: bits [s4|w4|h1|q1|g'1|c5] -> col n=w*64+h*32+c, oct o=s*4+q*2+g'
__global__ __launch_bounds__(256) void tok_prep(
    const float* __restrict__ z, const float* __restrict__ cw,
    unsigned short* __restrict__ e8, unsigned short* __restrict__ z8g) {
  int t = blockIdx.x * 256 + threadIdx.x;
  if (t < 1048576) {
    int blk = t >> 11, oct = (t >> 6) & 31, row = t & 63;
    *(int4*)(z8g + ((size_t)t << 3)) =
        pack8(z + (size_t)((blk << 6) + row) * KD + (oct << 3));
    return;
  }
  int t2 = t - 1048576;
  if (t2 >= 32768) return;
  int s = t2 >> 12, w2 = (t2 >> 8) & 15, h = (t2 >> 7) & 1,
      qq = (t2 >> 6) & 1, gp = (t2 >> 5) & 1, c = t2 & 31;
  int n = (w2 << 6) + (h << 5) + c;
  int o = (s << 2) + (qq << 1) + gp;
  *(int4*)(e8 + ((size_t)t2 << 3)) = pack8(cw + (size_t)(1 + n) * KD + (o << 3));
}

__global__ __launch_bounds__(1024, 4) void tok_mfma(
    const float* __restrict__ z, const float* __restrict__ mask,
    const float* __restrict__ cw, const unsigned short* __restrict__ e8,
    const unsigned short* __restrict__ z8g, float* __restrict__ out,
    float* __restrict__ ws) {
  __shared__ __align__(16) unsigned short A_s[16640];  // 32 planes x 1040 B
  __shared__ __align__(16) unsigned short B_s[32768];  // 16 waves x 2 x 2 KB
  __shared__ unsigned wkey[16][2][65];
  __shared__ float wsum[16][65];
  __shared__ float lse_s[64];
  __shared__ float exv_s[64][4];
  __shared__ int exi_s[64][4];
  __shared__ int argi[64];
  __shared__ float mask_s[64];
  __shared__ float cred[16], sred[16];

  const int tid = threadIdx.x;
  const int lane = tid & 63;
  const int w = tid >> 6;   // 0..15
  const int g = lane >> 4;  // 0..3
  const int lm = lane & 15;
  const int q = g >> 1, g2 = g & 1;
  const int n0 = blockIdx.x << 6;  // 64 rows per block

  unsigned short* Bw = B_s + (w << 11);  // 4 KB (2048 ushorts) per wave

  // ---- prologue: stage A (wave w stages oct-planes 2w,2w+1); mask ----
  {
    const unsigned short* asrc =
        z8g + ((((size_t)blockIdx.x << 11) + (w << 7)) << 3) + (lane << 3);
    gl_lds16(asrc, A_s + (w << 1) * 520);
    gl_lds16(asrc + 512, A_s + ((w << 1) + 1) * 520);
  }
  if (tid < 64) mask_s[tid] = mask[n0 + tid];
  __syncthreads();  // A visible to all waves; drains vmcnt

  auto stage_half = [&](int s2, int h2, int bufb) {
    const unsigned short* src =
        e8 + ((size_t)((((s2 << 4) + w) << 2) + (h2 << 1)) << 9) + (lane << 3);
    unsigned short* dst = Bw + (bufb << 10);
    gl_lds16(src, dst);        // chunk q=0 (1 KB)
    gl_lds16(src + 512, dst + 512);  // chunk q=1
  };
  stage_half(0, 0, 0);  // half 0 -> buf0
  stage_half(0, 1, 1);  // half 1 -> buf1

  f32x4 acc[4][4];
  const f32x4 zzero = {0.f, 0.f, 0.f, 0.f};
#pragma unroll
  for (int mt = 0; mt < 4; ++mt)
#pragma unroll
    for (int nt = 0; nt < 4; ++nt) acc[mt][nt] = zzero;

  const int boff = (q << 9) + (g2 << 8) + (lm << 3);  // ushort offset in chunk

  // ---- K-loop: 8 steps x 2 half-phases, counted vmcnt(2), 0 barriers ----
#pragma unroll 1
  for (int s = 0; s < 8; ++s) {
    asm volatile("s_waitcnt vmcnt(2)" ::: "memory");  // half 2s landed
    bf16x8 a[4];
#pragma unroll
    for (int mt = 0; mt < 4; ++mt)
      a[mt] = *(const bf16x8*)(A_s + ((s << 2) + g) * 520 +
                               (((mt << 4) + lm) << 3));
#pragma unroll
    for (int l = 0; l < 2; ++l) {
      bf16x8 b = *(const bf16x8*)(Bw + boff + (l << 7));
#pragma unroll
      for (int mt = 0; mt < 4; ++mt)
        acc[mt][l] =
            __builtin_amdgcn_mfma_f32_16x16x32_bf16(a[mt], b, acc[mt][l], 0, 0, 0);
    }
    asm volatile("s_waitcnt lgkmcnt(0)" ::: "memory");  // buf0 reads done
    if (s < 7) stage_half(s + 1, 0, 0);                 // half 2s+2 -> buf0
    if (s < 7)
      asm volatile("s_waitcnt vmcnt(2)" ::: "memory");  // half 2s+1 landed
    else
      asm volatile("s_waitcnt vmcnt(0)" ::: "memory");  // last half
#pragma unroll
    for (int l = 0; l < 2; ++l) {
      bf16x8 b = *(const bf16x8*)(Bw + 1024 + boff + (l << 7));
#pragma unroll
      for (int mt = 0; mt < 4; ++mt)
        acc[mt][2 + l] = __builtin_amdgcn_mfma_f32_16x16x32_bf16(
            a[mt], b, acc[mt][2 + l], 0, 0, 0);
    }
    asm volatile("s_waitcnt lgkmcnt(0)" ::: "memory");  // buf1 reads done
    if (s < 7) stage_half(s + 1, 1, 1);                 // half 2s+3 -> buf1
  }

  // D layout: row = mt*16 + g*4 + j, col = w*64 + nt*16 + lm (R7-R9 verified)
  unsigned colpack[4];
#pragma unroll
  for (int nt = 0; nt < 4; ++nt)
    colpack[nt] = 1023u - (unsigned)((w << 6) + (nt << 4) + lm);

  // ---- phase1: per-wave top-2 keys + wave-local exp-sum ----
#pragma unroll
  for (int mt = 0; mt < 4; ++mt)
#pragma unroll
    for (int j = 0; j < 4; ++j) {
      const int r = (mt << 4) + (g << 2) + j;
      unsigned cur[4];
#pragma unroll
      for (int nt = 0; nt < 4; ++nt)
        cur[nt] = (foldf(acc[mt][nt][j]) & 0xFFFFFC00u) | colpack[nt];
      unsigned k1 = cur[0];
#pragma unroll
      for (int nt = 1; nt < 4; ++nt) k1 = k1 > cur[nt] ? k1 : cur[nt];
#pragma unroll
      for (int d = 1; d <= 8; d <<= 1) {
        unsigned o2 = __shfl_xor(k1, d);
        k1 = k1 > o2 ? k1 : o2;
      }
      const float mw = unfoldf(k1 & 0xFFFFFC00u);
      float sum = 0.f;
#pragma unroll
      for (int nt = 0; nt < 4; ++nt) sum += __expf(acc[mt][nt][j] - mw);
#pragma unroll
      for (int d = 1; d <= 8; d <<= 1) sum += __shfl_xor(sum, d);
#pragma unroll
      for (int nt = 0; nt < 4; ++nt)
        if (cur[nt] == k1) cur[nt] = 0u;
      unsigned k2 = cur[0];
#pragma unroll
      for (int nt = 1; nt < 4; ++nt) k2 = k2 > cur[nt] ? k2 : cur[nt];
#pragma unroll
      for (int d = 1; d <= 8; d <<= 1) {
        unsigned o2 = __shfl_xor(k2, d);
        k2 = k2 > o2 ? k2 : o2;
      }
      if (lm == 0) {
        wkey[w][0][r] = k1;
        wkey[w][1][r] = k2;
        wsum[w][r] = sum;
      }
    }
  __syncthreads();

  // ---- row stats: global top-4 + lse (64 threads) ----
  if (tid < 64) {
    const int r = tid;
    unsigned best[4] = {0u, 0u, 0u, 0u};
#pragma unroll
    for (int w2 = 0; w2 < 16; ++w2)
#pragma unroll
      for (int k = 0; k < 2; ++k) {
        unsigned x = wkey[w2][k][r];
#pragma unroll
        for (int p2 = 0; p2 < 4; ++p2) {
          unsigned mx = x > best[p2] ? x : best[p2];
          unsigned mn = x > best[p2] ? best[p2] : x;
          best[p2] = mx;
          x = mn;
        }
      }
    const float M = unfoldf(best[0] & 0xFFFFFC00u);
    float S = 0.f;
#pragma unroll
    for (int w2 = 0; w2 < 16; ++w2)
      S += wsum[w2][r] * __expf(unfoldf(wkey[w2][0][r] & 0xFFFFFC00u) - M);
    lse_s[r] = M + __logf(S);
#pragma unroll
    for (int p2 = 0; p2 < 4; ++p2)
      exi_s[r][p2] = (int)(1023u - (best[p2] & 0x3FFu));
  }
  __syncthreads();

  // ---- E4B: exact fp32 dots; 64 rows x 4 cand, 4 threads/dot ----
  {
    const int row = tid >> 4;
    const int cd = (tid >> 2) & 3;
    const int seg = tid & 3;  // 64-float segment
    const int cand = exi_s[row][cd];
    const float* er = cw + (size_t)(1 + cand) * KD + (seg << 6);
    const float* zr = z + (size_t)(n0 + row) * KD + (seg << 6);
    float s = 0.f;
#pragma unroll
    for (int i2 = 0; i2 < 16; ++i2) {
      float4 a4 = *(const float4*)(zr + (i2 << 2));
      float4 b4 = *(const float4*)(er + (i2 << 2));
      s += a4.x * b4.x + a4.y * b4.y + a4.z * b4.z + a4.w * b4.w;
    }
    s += __shfl_xor(s, 1);
    s += __shfl_xor(s, 2);
    if (seg == 0) exv_s[row][cd] = s;
  }
  __syncthreads();

  // ---- final argmax (exact, first-index tiebreak) + histogram ----
  if (tid < 64) {
    const int row = tid;
    float bv = exv_s[row][0];
    int bi = exi_s[row][0];
#pragma unroll
    for (int c = 1; c < 4; ++c) {
      float v = exv_s[row][c];
      int ci = exi_s[row][c];
      if (v > bv || (v == bv && ci < bi)) { bv = v; bi = ci; }
    }
    argi[row] = bi;
    atomicAdd(&ws[WS_HIST + bi], mask_s[row]);  // mask=1.0 adds: exact
  }
  __syncthreads();

  // ---- E5: losses (z from global/L3; keep e rows in regs for z_q) ----
  float csum = 0.f, ssum = 0.f;
  float4 evs[4];
  const bool has_prev = (n0 % TT) != 0;
#pragma unroll
  for (int i = 0; i < 4; ++i) {
    const int r = (i << 4) + w;
    const int c4 = lane << 2;
    const int idx = argi[r];
    const float4 ev = *(const float4*)&cw[(size_t)(1 + idx) * KD + c4];
    evs[i] = ev;
    const float4 zv = *(const float4*)&z[(size_t)(n0 + r) * KD + c4];
    const float mk = mask_s[r];
    float dx = zv.x - ev.x, dy = zv.y - ev.y, dz2 = zv.z - ev.z,
          dw = zv.w - ev.w;
    csum += mk * (dx * dx + dy * dy + dz2 * dz2 + dw * dw);
    if (r > 0 || has_prev) {
      const float4 pv = *(const float4*)&z[(size_t)(n0 + r - 1) * KD + c4];
      float ax = zv.x - pv.x, ay = zv.y - pv.y, az = zv.z - pv.z,
            aw = zv.w - pv.w;
      ssum += mk * (ax * ax + ay * ay + az * az + aw * aw);
    }
  }
#pragma unroll
  for (int d = 1; d <= 32; d <<= 1) {
    csum += __shfl_xor(csum, d);
    ssum += __shfl_xor(ssum, d);
  }
  if (lane == 0) { cred[w] = csum; sred[w] = ssum; }
  __syncthreads();
  if (tid == 0) {
    float cs = 0.f, ss2 = 0.f;
#pragma unroll
    for (int i = 0; i < 16; ++i) { cs += cred[i]; ss2 += sred[i]; }
    ws[WS_CSUM + blockIdx.x] = cs;
    ws[WS_SSUM + blockIdx.x] = ss2;
    float ms = 0.f;
    for (int r2 = 0; r2 < 64; ++r2) ms += mask_s[r2];
    ws[WS_MSUM + blockIdx.x] = ms;
  }

  // ---- stores dead-last: z_q then log_probs; no barriers after ----
#pragma unroll
  for (int i = 0; i < 4; ++i) {
    const int r = (i << 4) + w;
    *(float4*)&out[ZQ_OFF + (size_t)(n0 + r) * KD + (lane << 2)] = evs[i];
  }
#pragma unroll
  for (int mt = 0; mt < 4; ++mt)
#pragma unroll
    for (int j = 0; j < 4; ++j) {
      const int r = (mt << 4) + (g << 2) + j;
      const float lse = lse_s[r];
      size_t base = LP_OFF + (size_t)(n0 + r) * VV + (w << 6);
#pragma unroll
      for (int nt = 0; nt < 4; ++nt)
        out[base + (nt << 4) + lm] = acc[mt][nt][j] - lse;
    }
}

// ---------- fp32 fallback if ws too small (R3-lineage, verified) ----------
__global__ __launch_bounds__(256, 2) void tok_fb(
    const float* __restrict__ z, const float* __restrict__ mask,
    const float* __restrict__ cw, float* __restrict__ out,
    float* __restrict__ ws) {
  __shared__ __align__(16) float z_s[32][KD];
  __shared__ int argi_s[32];
  __shared__ float cred[4], sred[4];
  const int tid = threadIdx.x;
  const int lane = tid & 63;
  const int wave = tid >> 6;
  const int n0 = blockIdx.x * 32;
  const float* e = cw + KD;
#pragma unroll
  for (int i = 0; i < 8; ++i) {
    int seg = wave * 8 + i;
    gl_lds16(&z[(size_t)(n0 + seg) * KD + lane * 4], &z_s[seg][0]);
  }
  __syncthreads();
  float acc[8][16];
#pragma unroll
  for (int r = 0; r < 8; ++r)
#pragma unroll
    for (int m = 0; m < 16; ++m) acc[r][m] = 0.f;
#pragma unroll 1
  for (int i = 0; i < 64; ++i) {
    float4 ef[16];
#pragma unroll
    for (int m = 0; m < 16; ++m)
      ef[m] = *(const float4*)&e[(size_t)((m << 6) + lane) * KD + (i << 2)];
    float4 zf[8];
#pragma unroll
    for (int rr = 0; rr < 8; ++rr)
      zf[rr] = *(const float4*)&z_s[(wave << 3) + rr][i << 2];
#pragma unroll
    for (int m = 0; m < 16; ++m)
#pragma unroll
      for (int rr = 0; rr < 8; ++rr)
        acc[rr][m] += zf[rr].x * ef[m].x + zf[rr].y * ef[m].y +
                      zf[rr].z * ef[m].z + zf[rr].w * ef[m].w;
  }
  const int rowbase = wave << 3;
#pragma unroll
  for (int rr = 0; rr < 8; ++rr) {
    float mv = acc[rr][0];
    int mc = lane;
#pragma unroll
    for (int m = 1; m < 16; ++m) {
      float v = acc[rr][m];
      int c = (m << 6) + lane;
      bool tk = v > mv;
      mc = tk ? c : mc;
      mv = tk ? v : mv;
    }
#pragma unroll
    for (int d = 32; d >= 1; d >>= 1) {
      float ov = __shfl_xor(mv, d);
      int oc = __shfl_xor(mc, d);
      bool tk = (ov > mv) || (ov == mv && oc < mc);
      mv = tk ? ov : mv;
      mc = tk ? oc : mc;
    }
    float sum = 0.f;
#pragma unroll
    for (int m = 0; m < 16; ++m) sum += __expf(acc[rr][m] - mv);
#pragma unroll
    for (int d = 32; d >= 1; d >>= 1) sum += __shfl_xor(sum, d);
    float lse = mv + __logf(sum);
    size_t base = LP_OFF + (size_t)(n0 + rowbase + rr) * VV;
#pragma unroll
    for (int m = 0; m < 16; ++m) out[base + (m << 6) + lane] = acc[rr][m] - lse;
    if (lane == 0) {
      argi_s[rowbase + rr] = mc;
      atomicAdd(&ws[WS_HIST + mc], mask[n0 + rowbase + rr]);
    }
  }
  __syncthreads();
  float csum = 0.f, ssum = 0.f;
  const bool has_prev = (n0 % TT) != 0;
#pragma unroll
  for (int i = 0; i < 8; ++i) {
    int q = i * 256 + tid;
    int r = q >> 6;
    int c4 = (q & 63) << 2;
    int idx = argi_s[r];
    const float4 ev = *(const float4*)&e[(size_t)idx * KD + c4];
    const float4 zv = *(const float4*)&z_s[r][c4];
    *(float4*)&out[ZQ_OFF + (size_t)(n0 + r) * KD + c4] = ev;
    float mk = mask[n0 + r];
    float dx = zv.x - ev.x, dy = zv.y - ev.y, dz2 = zv.z - ev.z, dw = zv.w - ev.w;
    csum += mk * (dx * dx + dy * dy + dz2 * dz2 + dw * dw);
    if (r > 0) {
      const float4 pv = *(const float4*)&z_s[r - 1][c4];
      float ax = zv.x - pv.x, ay = zv.y - pv.y, az = zv.z - pv.z, aw = zv.w - pv.w;
      ssum += mk * (ax * ax + ay * ay + az * az + aw * aw);
    } else if (has_prev) {
      const float4 pv = *(const float4*)&z[(size_t)(n0 - 1) * KD + c4];
      float ax = zv.x - pv.x, ay = zv.y - pv.y, az = zv.z - pv.z, aw = zv.w - pv.w;
      ssum += mk * (ax * ax + ay * ay + az * az + aw * aw);
    }
  }
#pragma unroll
  for (int d = 32; d >= 1; d >>= 1) {
    csum += __shfl_xor(csum, d);
    ssum += __shfl_xor(ssum, d);
  }
  if (lane == 0) { cred[wave] = csum; sred[wave] = ssum; }
  __syncthreads();
  if (tid == 0) {
    ws[WS_CSUM + blockIdx.x] = cred[0] + cred[1] + cred[2] + cred[3];
    ws[WS_SSUM + blockIdx.x] = sred[0] + sred[1] + sred[2] + sred[3];
    float ms = 0.f;
    for (int r2 = 0; r2 < 32; ++r2) ms += mask[n0 + r2];
    ws[WS_MSUM + blockIdx.x] = ms;
  }
}

template <int NB>
__global__ __launch_bounds__(1024) void tok_final(const float* __restrict__ ws,
                                                  float* __restrict__ out) {
  const int t = threadIdx.x;
  const int lane = t & 63, w = t >> 6;
  __shared__ float red[16];
  auto blockReduce = [&](float v) -> float {
#pragma unroll
    for (int d = 32; d >= 1; d >>= 1) v += __shfl_xor(v, d);
    __syncthreads();
    if (lane == 0) red[w] = v;
    __syncthreads();
    float s = 0.f;
#pragma unroll
    for (int i = 0; i < 16; ++i) s += red[i];
    return s;
  };
  float Mtot = blockReduce(t < NB ? ws[WS_MSUM + t] : 0.f);
  float Ctot = blockReduce(t < NB ? ws[WS_CSUM + t] : 0.f);
  float Stot = blockReduce(t < NB ? ws[WS_SSUM + t] : 0.f);
  float prob = ws[WS_HIST + t] / Mtot;
  float psum = blockReduce(prob);
  out[EM_OFF + t] = prob / psum;
  if (t == 0) {
    float vc = Mtot * (float)KD;
    out[0] = Stot / vc;  // smoothness_loss
    out[1] = Ctot / vc;  // commitment_loss
  }
}

extern "C" void kernel_launch(void* const* d_in, const int* in_sizes, int n_in,
                              void* d_out, int out_size, void* d_ws,
                              size_t ws_size, hipStream_t stream) {
  const float* z = (const float*)d_in[0];
  const float* mask = (const float*)d_in[1];
  const float* cw = (const float*)d_in[2];
  float* out = (float*)d_out;
  float* ws = (float*)d_ws;
  hipMemsetAsync(ws, 0, 1024 * sizeof(float), stream);  // histogram zeros
  if (ws_size >= WS_NEED_Z) {
    unsigned short* e8 = (unsigned short*)(ws + WS_E8);
    unsigned short* z8g = (unsigned short*)(ws + WS_Z8G);
    tok_prep<<<4224, 256, 0, stream>>>(z, cw, e8, z8g);
    tok_mfma<<<NB2, 1024, 0, stream>>>(z, mask, cw, e8, z8g, out, ws);
    tok_final<NB2><<<1, 1024, 0, stream>>>(ws, out);
  } else {
    tok_fb<<<NROW / 32, 256, 0, stream>>>(z, mask, cw, out, ws);
    tok_final<NROW / 32><<<1, 1024, 0, stream>>>(ws, out);
  }
}